// Round 6
// baseline (365.736 us; speedup 1.0000x reference)
//
#include <hip/hip_runtime.h>
#include <math.h>
#include <stdint.h>

#define LSEQ 8192
#define DIN  512
#define NB   8
#define NBH  4
#define NO   1024

typedef __bf16 bf16x8 __attribute__((ext_vector_type(8)));
typedef float f32x16 __attribute__((ext_vector_type(16)));

// RNE float->bf16 pair pack; LLVM fptrunc to bfloat is RNE, so this is
// bit-identical to the integer round-and-shift trick but compiles to
// v_cvt_pk_bf16_f32 on gfx950.
__device__ __forceinline__ uint32_t pack_bf16_rne(float lo, float hi) {
    uint16_t l = __builtin_bit_cast(uint16_t, (__bf16)lo);
    uint16_t h = __builtin_bit_cast(uint16_t, (__bf16)hi);
    return (uint32_t)l | ((uint32_t)h << 16);
}
__device__ __forceinline__ float bf16_lo(uint32_t w) {
    return __builtin_bit_cast(float, w << 16);
}
__device__ __forceinline__ float bf16_hi(uint32_t w) {
    return __builtin_bit_cast(float, w & 0xFFFF0000u);
}

// async global->LDS, 16B per lane; LDS dest = wave-uniform base + lane*16
__device__ __forceinline__ void gl_lds16(const void* g, void* l) {
    __builtin_amdgcn_global_load_lds(
        (const __attribute__((address_space(1))) void*)g,
        (__attribute__((address_space(3))) void*)l, 16, 0, 0);
}

// Fragment-major tile layout (A and B identical structure):
//   per 128-row(col) x 512-k tile: 16 iter-slices of 2048 words; within a
//   slice, chunk c = ((mb*4 + q)*32 + m31) holds the 16B fragment for
//   row/col (mb*32+m31), k2-group q (k2 = it*16 + q*4 + wic).
//   A ds_read_b128 for (mb, kh) is then base + lane*16 -> conflict-free.

// ---------------- Kernel 1: weight norm -> bf16, fragment-major -----------
__global__ void norm_kernel(const float* __restrict__ W, uint32_t* __restrict__ Wnb) {
    const int o = blockIdx.x;
    const int lane = threadIdx.x;  // 0..63
    const float* row = W + (size_t)o * DIN;
    float4 v0 = *(const float4*)(row + lane * 4);
    float4 v1 = *(const float4*)(row + 256 + lane * 4);
    float s = v0.x * v0.x + v0.y * v0.y + v0.z * v0.z + v0.w * v0.w
            + v1.x * v1.x + v1.y * v1.y + v1.z * v1.z + v1.w * v1.w;
#pragma unroll
    for (int m = 32; m; m >>= 1) s += __shfl_xor(s, m, 64);
    const float sq = 22.62741699796952f;  // sqrt(512)
    const float scale = 1.0f / ((1e-4f + sqrtf(s) / sq) * sq);
    uint2 w0, w1;
    w0.x = pack_bf16_rne(v0.x * scale, v0.y * scale);
    w0.y = pack_bf16_rne(v0.z * scale, v0.w * scale);
    w1.x = pack_bf16_rne(v1.x * scale, v1.y * scale);
    w1.y = pack_bf16_rne(v1.z * scale, v1.w * scale);
    // w0 covers k2 = 2*lane, 2*lane+1 ; w1 covers k2 = 128 + 2*lane, +1
    const int ot = o >> 7, mb = (o >> 5) & 3, m31 = o & 31;
    const int it0 = lane >> 3;          // k2>>4
    const int q   = (lane >> 1) & 3;    // (k2>>2)&3
    const int wic = (lane & 1) * 2;     // k2&3
    uint32_t* base = Wnb + (size_t)ot * 32768 + ((mb * 4 + q) * 32 + m31) * 4 + wic;
    *(uint2*)&base[(size_t)it0 * 2048] = w0;
    *(uint2*)&base[(size_t)(it0 + 8) * 2048] = w1;
}

// ---------------- Kernel 1b: x fp32 -> pair-packed bf16, fragment-major ----
// Per-half (4 batches). Block = (b-local, lt, 32-k2 chunk): reads 32 KB
// coalesced, XOR-swizzled LDS transpose (read phase uniform 2-way = free),
// writes fragment-major chunks.
__global__ __launch_bounds__(256)
void xpack_kernel(const float* __restrict__ x, uint32_t* __restrict__ xp, int b0) {
    __shared__ uint32_t sT[32 * 132];  // stride 132: 16B-aligned rows
    const int t  = threadIdx.x;
    const int bx = blockIdx.x;  // lt = bx>>3, ch = bx&7
    const int by = blockIdx.y;  // 0..3 local batch
    const int b  = b0 + by;     // global batch
    const int lt = bx >> 3;
    const int ch = bx & 7;

    const float* xb = x + (size_t)b * DIN * LSEQ + lt * 128;
#pragma unroll
    for (int j = 0; j < 4; ++j) {
        const int idx = j * 256 + t;  // 0..1023
        const int k2l = idx >> 5;     // 0..31
        const int lg  = idx & 31;
        const float* r0 = xb + (size_t)(2 * (ch * 32 + k2l)) * LSEQ + lg * 4;
        float4 a = *(const float4*)r0;
        float4 c = *(const float4*)(r0 + LSEQ);
        uint4 wv;
        wv.x = pack_bf16_rne(a.x, c.x);
        wv.y = pack_bf16_rne(a.y, c.y);
        wv.z = pack_bf16_rne(a.z, c.z);
        wv.w = pack_bf16_rne(a.w, c.w);
        const int sc = lg ^ (k2l >> 2);  // swizzled 16B chunk within row
        *(uint4*)&sT[k2l * 132 + sc * 4] = wv;
    }
    __syncthreads();
    uint32_t* ob = xp + (size_t)(by * 64 + lt) * 32768;
#pragma unroll
    for (int j = 0; j < 4; ++j) {
        const int idx = j * 256 + t;  // 0..1023
        const int lp  = idx >> 3;     // l' 0..127
        const int gq  = idx & 7;      // local k2 group of 4 (rows gq*4..+3)
        // stored chunk for (row r, col lp) is (lp>>2) ^ (r>>2); r>>2 == gq
        const int cb_ = (((lp >> 2) ^ gq) << 2) + (lp & 3);
        uint4 wv;
        wv.x = sT[(gq * 4 + 0) * 132 + cb_];
        wv.y = sT[(gq * 4 + 1) * 132 + cb_];
        wv.z = sT[(gq * 4 + 2) * 132 + cb_];
        wv.w = sT[(gq * 4 + 3) * 132 + cb_];
        const int itl   = ch * 2 + (gq >> 2);                 // k2>>4
        const int q     = gq & 3;                             // (k2>>2)&3
        const int chunk = ((lp >> 5) * 4 + q) * 32 + (lp & 31);
        *(uint4*)&ob[(size_t)itl * 2048 + chunk * 4] = wv;
    }
}

// ---------------- Kernel 2: bf16 MFMA GEMM, fragment-major LDS ------------
// Per-half (grid y = 4, local batch). R2 structure: 2 buffers, one
// __syncthreads per K-step; xp and fbp indexed by local batch.
__global__ __launch_bounds__(256)
void gemm_kernel(const uint32_t* __restrict__ Wnb, const uint32_t* __restrict__ xp,
                 uint32_t* __restrict__ fbp) {
    __shared__ uint32_t sA[2][2048];  // 2 x 8 KB
    __shared__ uint32_t sB[2][2048];  // 2 x 8 KB

    const int tid  = threadIdx.x;
    const int lane = tid & 63;
    const int w    = tid >> 6;
    const int wm   = w & 1, wn = w >> 1;

    const int bx  = blockIdx.x;
    const int xcd = bx & 7;
    const int t   = bx >> 3;
    const int o0t = t & 7;
    const int o0  = o0t * 128;
    const int ltg = xcd + ((t >> 3) << 3);
    const int l0  = ltg * 128;
    const int by  = blockIdx.y;  // local batch 0..3

    // staging sources: contiguous 1KB per instruction (wave w stages
    // chunk-blocks j = 2w and 2w+1 of both A and B)
    const uint32_t* gA = Wnb + (size_t)o0t * 32768 + (w * 2) * 256 + lane * 4;
    const uint32_t* gB = xp + (size_t)(by * 64 + ltg) * 32768 + (w * 2) * 256 + lane * 4;

    f32x16 acc[2][2];
#pragma unroll
    for (int i = 0; i < 2; ++i)
#pragma unroll
        for (int j = 0; j < 2; ++j)
#pragma unroll
            for (int r = 0; r < 16; ++r) acc[i][j][r] = 0.f;

#define STAGE(it, bs)                                               \
    do {                                                            \
        gl_lds16(gA + (size_t)(it) * 2048, &sA[bs][w * 512]);       \
        gl_lds16(gA + (size_t)(it) * 2048 + 256, &sA[bs][w * 512 + 256]); \
        gl_lds16(gB + (size_t)(it) * 2048, &sB[bs][w * 512]);       \
        gl_lds16(gB + (size_t)(it) * 2048 + 256, &sB[bs][w * 512 + 256]); \
    } while (0)

    STAGE(0, 0);
#pragma unroll 2
    for (int it = 0; it < 16; ++it) {
        const int cb = it & 1;
        __syncthreads();  // drains vmcnt(0): buf[cb] ready, prev compute done
        if (it + 1 < 16) STAGE(it + 1, cb ^ 1);
        const uint32_t* cA = sA[cb];
        const uint32_t* cB = sB[cb];
#pragma unroll
        for (int kh = 0; kh < 2; ++kh) {
            bf16x8 af[2], bfr[2];
#pragma unroll
            for (int ms = 0; ms < 2; ++ms)
                af[ms] = *(const bf16x8*)&cA[((wm * 2 + ms) * 4 + kh * 2) * 128 + lane * 4];
#pragma unroll
            for (int ns = 0; ns < 2; ++ns)
                bfr[ns] = *(const bf16x8*)&cB[((wn * 2 + ns) * 4 + kh * 2) * 128 + lane * 4];
#pragma unroll
            for (int ms = 0; ms < 2; ++ms)
#pragma unroll
                for (int ns = 0; ns < 2; ++ns)
                    acc[ms][ns] = __builtin_amdgcn_mfma_f32_32x32x16_bf16(
                        af[ms], bfr[ns], acc[ms][ns], 0, 0, 0);
        }
    }
#undef STAGE

    // epilogue: pack adjacent-o pairs (adjacent acc regs) -> one uint32 word
    uint32_t* fbp_b = fbp + (size_t)by * 512 * LSEQ + l0;
#pragma unroll
    for (int ms = 0; ms < 2; ++ms)
#pragma unroll
        for (int ns = 0; ns < 2; ++ns) {
            const f32x16 a = acc[ms][ns];
            const int rb = o0 + wm * 64 + ms * 32 + 4 * (lane >> 5);  // even
            const int cc = wn * 64 + ns * 32 + (lane & 31);
#pragma unroll
            for (int rp = 0; rp < 8; ++rp) {
                const int r = rp * 2;
                const int row = rb + (r & 3) + 8 * (r >> 2);  // even
                fbp_b[(size_t)(row >> 1) * LSEQ + cc] = pack_bf16_rne(a[r], a[r + 1]);
            }
        }
}

// ---------------- Kernel 3: minGRU scan, direct-load version --------------
// Per-half. 1024 threads = 16 waves; one block per (b-local, dir, ch-pair).
// Thread t owns l in [t*8, t*8+8), both channels (bf16 lo/hi of fbp word).
__global__ __launch_bounds__(1024)
void scan_kernel(const uint32_t* __restrict__ fbp, float* __restrict__ out, int b0) {
    __shared__ float sA0[16], sB0[16], sA1[16], sB1[16];

    const int bx  = blockIdx.x;  // 0..255
    const int by  = blockIdx.y;  // local batch 0..3
    const int b   = b0 + by;     // global batch
    const int dir = bx >> 7;
    const int p   = bx & 127;
    const int o2h = dir * 256 + p;
    const int o2g = dir * 256 + 128 + p;

    const int t    = threadIdx.x;  // 0..1023
    const int lane = t & 63;
    const int w    = t >> 6;       // 0..15

    const uint32_t* hp = fbp + ((size_t)by * 512 + o2h) * LSEQ + t * 8;
    const uint32_t* gp = fbp + ((size_t)by * 512 + o2g) * LSEQ + t * 8;
    const uint4 h4a = *(const uint4*)(hp);
    const uint4 h4b = *(const uint4*)(hp + 4);
    const uint4 g4a = *(const uint4*)(gp);
    const uint4 g4b = *(const uint4*)(gp + 4);

    float av0[8], vv0[8], av1[8], vv1[8];
    {
        const uint32_t hws[8] = {h4a.x, h4a.y, h4a.z, h4a.w, h4b.x, h4b.y, h4b.z, h4b.w};
        const uint32_t gws[8] = {g4a.x, g4a.y, g4a.z, g4a.w, g4b.x, g4b.y, g4b.z, g4b.w};
#pragma unroll
        for (int s = 0; s < 8; ++s) {
            {
                float g_ = fminf(fmaxf(bf16_lo(gws[s]), -30.f), 30.f);
                float eg = __expf(g_);
                float a  = rsqrtf(fmaf(eg, eg, 1.f));
                float h_ = bf16_lo(hws[s]);
                av0[s] = a;
                vv0[s] = a * eg * copysignf(fmaxf(fabsf(h_), 1e-6f), h_);
            }
            {
                float g_ = fminf(fmaxf(bf16_hi(gws[s]), -30.f), 30.f);
                float eg = __expf(g_);
                float a  = rsqrtf(fmaf(eg, eg, 1.f));
                float h_ = bf16_hi(hws[s]);
                av1[s] = a;
                vv1[s] = a * eg * copysignf(fmaxf(fabsf(h_), 1e-6f), h_);
            }
        }
    }

    // ---- local composites (scan order) ----
    float A0 = 1.f, B0 = 0.f, A1 = 1.f, B1 = 0.f;
    if (dir == 0) {
#pragma unroll
        for (int i = 0; i < 8; ++i) {
            B0 = fmaf(av0[i], B0, vv0[i]); A0 *= av0[i];
            B1 = fmaf(av1[i], B1, vv1[i]); A1 *= av1[i];
        }
    } else {
#pragma unroll
        for (int i = 7; i >= 0; --i) {
            B0 = fmaf(av0[i], B0, vv0[i]); A0 *= av0[i];
            B1 = fmaf(av1[i], B1, vv1[i]); A1 *= av1[i];
        }
    }

    // ---- wave scan of affine composites ----
    if (dir == 0) {
#pragma unroll
        for (int off = 1; off < 64; off <<= 1) {
            float Ap0 = __shfl_up(A0, (unsigned)off, 64), Bp0 = __shfl_up(B0, (unsigned)off, 64);
            float Ap1 = __shfl_up(A1, (unsigned)off, 64), Bp1 = __shfl_up(B1, (unsigned)off, 64);
            if (lane >= off) {
                B0 = fmaf(A0, Bp0, B0); A0 *= Ap0;
                B1 = fmaf(A1, Bp1, B1); A1 *= Ap1;
            }
        }
        if (lane == 63) { sA0[w] = A0; sB0[w] = B0; sA1[w] = A1; sB1[w] = B1; }
    } else {
#pragma unroll
        for (int off = 1; off < 64; off <<= 1) {
            float Ap0 = __shfl_down(A0, (unsigned)off, 64), Bp0 = __shfl_down(B0, (unsigned)off, 64);
            float Ap1 = __shfl_down(A1, (unsigned)off, 64), Bp1 = __shfl_down(B1, (unsigned)off, 64);
            if (lane + off < 64) {
                B0 = fmaf(A0, Bp0, B0); A0 *= Ap0;
                B1 = fmaf(A1, Bp1, B1); A1 *= Ap1;
            }
        }
        if (lane == 0) { sA0[w] = A0; sB0[w] = B0; sA1[w] = A1; sB1[w] = B1; }
    }
    __syncthreads();

    // ---- cross-wave combine (16 waves) ----
    float WB0 = 0.f, WB1 = 0.f;
    if (dir == 0) {
        for (int wv = 0; wv < w; ++wv) {
            WB0 = fmaf(sA0[wv], WB0, sB0[wv]);
            WB1 = fmaf(sA1[wv], WB1, sB1[wv]);
        }
    } else {
        for (int wv = 15; wv > w; --wv) {
            WB0 = fmaf(sA0[wv], WB0, sB0[wv]);
            WB1 = fmaf(sA1[wv], WB1, sB1[wv]);
        }
    }
    float eA0, eB0, eA1, eB1;
    if (dir == 0) {
        eA0 = __shfl_up(A0, 1u, 64); eB0 = __shfl_up(B0, 1u, 64);
        eA1 = __shfl_up(A1, 1u, 64); eB1 = __shfl_up(B1, 1u, 64);
        if (lane == 0) { eA0 = 1.f; eB0 = 0.f; eA1 = 1.f; eB1 = 0.f; }
    } else {
        eA0 = __shfl_down(A0, 1u, 64); eB0 = __shfl_down(B0, 1u, 64);
        eA1 = __shfl_down(A1, 1u, 64); eB1 = __shfl_down(B1, 1u, 64);
        if (lane == 63) { eA0 = 1.f; eB0 = 0.f; eA1 = 1.f; eB1 = 0.f; }
    }
    float H0 = fmaf(eA0, WB0, eB0);
    float H1 = fmaf(eA1, WB1, eB1);

    // ---- final replay (results into vv, memory order) ----
    if (dir == 0) {
#pragma unroll
        for (int i = 0; i < 8; ++i) {
            H0 = fmaf(av0[i], H0, vv0[i]); vv0[i] = H0;
            H1 = fmaf(av1[i], H1, vv1[i]); vv1[i] = H1;
        }
    } else {
#pragma unroll
        for (int i = 7; i >= 0; --i) {
            H0 = fmaf(av0[i], H0, vv0[i]); vv0[i] = H0;
            H1 = fmaf(av1[i], H1, vv1[i]); vv1[i] = H1;
        }
    }

    // ---- direct stores ----
    float* orow0 = out + ((size_t)b * 512 + dir * 256 + 2 * p) * LSEQ + t * 8;
    float* orow1 = orow0 + LSEQ;  // channel 2p+1
    *(float4*)(orow0)     = make_float4(vv0[0], vv0[1], vv0[2], vv0[3]);
    *(float4*)(orow0 + 4) = make_float4(vv0[4], vv0[5], vv0[6], vv0[7]);
    *(float4*)(orow1)     = make_float4(vv1[0], vv1[1], vv1[2], vv1[3]);
    *(float4*)(orow1 + 4) = make_float4(vv1[4], vv1[5], vv1[6], vv1[7]);
}

// ---------------- launch ----------------
// Batch-sliced (2 halves x 4 batches): xp/fbp hold only the live half so the
// gemm->scan intermediate stays L3-resident; workspace 199 MB -> ~100 MB.
extern "C" void kernel_launch(void* const* d_in, const int* in_sizes, int n_in,
                              void* d_out, int out_size, void* d_ws, size_t ws_size,
                              hipStream_t stream) {
    const float* x = (const float*)d_in[0];  // (8, 512, 8192)
    const float* W = (const float*)d_in[1];  // (1024, 512, 1)
    float* out = (float*)d_out;              // (8, 512, 8192)

    uint32_t* Wnb = (uint32_t*)d_ws;                                   // 1 MB
    uint32_t* fbp = (uint32_t*)((char*)d_ws + (size_t)NO * DIN * 2);   // 67 MB
    uint32_t* xp  = (uint32_t*)((char*)d_ws + (size_t)NO * DIN * 2
                                + (size_t)NBH * 512 * LSEQ * 4);       // 32 MB

    norm_kernel<<<dim3(NO), dim3(64), 0, stream>>>(W, Wnb);
    for (int h = 0; h < 2; ++h) {
        xpack_kernel<<<dim3(512, NBH), dim3(256), 0, stream>>>(x, xp, h * NBH);
        gemm_kernel<<<dim3(512, NBH), dim3(256), 0, stream>>>(Wnb, xp, fbp);
        scan_kernel<<<dim3(256, NBH), dim3(1024), 0, stream>>>(fbp, out, h * NBH);
    }
}

// Round 7
// 350.757 us; speedup vs baseline: 1.0427x; 1.0427x over previous
//
#include <hip/hip_runtime.h>
#include <math.h>
#include <stdint.h>

#define LSEQ 8192
#define DIN  512
#define NB   8
#define NBH  4
#define NO   1024

typedef __bf16 bf16x8 __attribute__((ext_vector_type(8)));
typedef float f32x16 __attribute__((ext_vector_type(16)));

// RNE float->bf16 pair pack (fptrunc to bfloat is RNE; emits v_cvt_pk_bf16_f32)
__device__ __forceinline__ uint32_t pack_bf16_rne(float lo, float hi) {
    uint16_t l = __builtin_bit_cast(uint16_t, (__bf16)lo);
    uint16_t h = __builtin_bit_cast(uint16_t, (__bf16)hi);
    return (uint32_t)l | ((uint32_t)h << 16);
}
__device__ __forceinline__ float bf16_lo(uint32_t w) {
    return __builtin_bit_cast(float, w << 16);
}
__device__ __forceinline__ float bf16_hi(uint32_t w) {
    return __builtin_bit_cast(float, w & 0xFFFF0000u);
}

// async global->LDS, 16B per lane; LDS dest = wave-uniform base + lane*16
__device__ __forceinline__ void gl_lds16(const void* g, void* l) {
    __builtin_amdgcn_global_load_lds(
        (const __attribute__((address_space(1))) void*)g,
        (__attribute__((address_space(3))) void*)l, 16, 0, 0);
}

// Fragment-major tile layout (A and B identical structure):
//   per 128-row(col) x 512-k tile: 16 iter-slices of 2048 words; within a
//   slice, chunk c = ((mb*4 + q)*32 + m31) holds the 16B fragment for
//   row/col (mb*32+m31), k2-group q (k2 = it*16 + q*4 + wic).
//   A ds_read_b128 for (mb, kh) is then base + lane*16 -> conflict-free.

// ---------------- Kernel 1: weight norm -> bf16, fragment-major -----------
__global__ void norm_kernel(const float* __restrict__ W, uint32_t* __restrict__ Wnb) {
    const int o = blockIdx.x;
    const int lane = threadIdx.x;  // 0..63
    const float* row = W + (size_t)o * DIN;
    float4 v0 = *(const float4*)(row + lane * 4);
    float4 v1 = *(const float4*)(row + 256 + lane * 4);
    float s = v0.x * v0.x + v0.y * v0.y + v0.z * v0.z + v0.w * v0.w
            + v1.x * v1.x + v1.y * v1.y + v1.z * v1.z + v1.w * v1.w;
#pragma unroll
    for (int m = 32; m; m >>= 1) s += __shfl_xor(s, m, 64);
    const float sq = 22.62741699796952f;  // sqrt(512)
    const float scale = 1.0f / ((1e-4f + sqrtf(s) / sq) * sq);
    uint2 w0, w1;
    w0.x = pack_bf16_rne(v0.x * scale, v0.y * scale);
    w0.y = pack_bf16_rne(v0.z * scale, v0.w * scale);
    w1.x = pack_bf16_rne(v1.x * scale, v1.y * scale);
    w1.y = pack_bf16_rne(v1.z * scale, v1.w * scale);
    // w0 covers k2 = 2*lane, 2*lane+1 ; w1 covers k2 = 128 + 2*lane, +1
    const int ot = o >> 7, mb = (o >> 5) & 3, m31 = o & 31;
    const int it0 = lane >> 3;          // k2>>4
    const int q   = (lane >> 1) & 3;    // (k2>>2)&3
    const int wic = (lane & 1) * 2;     // k2&3
    uint32_t* base = Wnb + (size_t)ot * 32768 + ((mb * 4 + q) * 32 + m31) * 4 + wic;
    *(uint2*)&base[(size_t)it0 * 2048] = w0;
    *(uint2*)&base[(size_t)(it0 + 8) * 2048] = w1;
}

// ---------------- Kernel 1b: x fp32 -> pair-packed bf16, fragment-major ----
__global__ __launch_bounds__(256)
void xpack_kernel(const float* __restrict__ x, uint32_t* __restrict__ xp, int b0) {
    __shared__ uint32_t sT[32 * 132];  // stride 132: 16B-aligned rows
    const int t  = threadIdx.x;
    const int bx = blockIdx.x;  // lt = bx>>3, ch = bx&7
    const int by = blockIdx.y;  // 0..3 local batch
    const int b  = b0 + by;     // global batch
    const int lt = bx >> 3;
    const int ch = bx & 7;

    const float* xb = x + (size_t)b * DIN * LSEQ + lt * 128;
#pragma unroll
    for (int j = 0; j < 4; ++j) {
        const int idx = j * 256 + t;  // 0..1023
        const int k2l = idx >> 5;     // 0..31
        const int lg  = idx & 31;
        const float* r0 = xb + (size_t)(2 * (ch * 32 + k2l)) * LSEQ + lg * 4;
        float4 a = *(const float4*)r0;
        float4 c = *(const float4*)(r0 + LSEQ);
        uint4 wv;
        wv.x = pack_bf16_rne(a.x, c.x);
        wv.y = pack_bf16_rne(a.y, c.y);
        wv.z = pack_bf16_rne(a.z, c.z);
        wv.w = pack_bf16_rne(a.w, c.w);
        const int sc = lg ^ (k2l >> 2);  // swizzled 16B chunk within row
        *(uint4*)&sT[k2l * 132 + sc * 4] = wv;
    }
    __syncthreads();
    uint32_t* ob = xp + (size_t)(by * 64 + lt) * 32768;
#pragma unroll
    for (int j = 0; j < 4; ++j) {
        const int idx = j * 256 + t;  // 0..1023
        const int lp  = idx >> 3;     // l' 0..127
        const int gq  = idx & 7;      // local k2 group of 4 (rows gq*4..+3)
        const int cb_ = (((lp >> 2) ^ gq) << 2) + (lp & 3);
        uint4 wv;
        wv.x = sT[(gq * 4 + 0) * 132 + cb_];
        wv.y = sT[(gq * 4 + 1) * 132 + cb_];
        wv.z = sT[(gq * 4 + 2) * 132 + cb_];
        wv.w = sT[(gq * 4 + 3) * 132 + cb_];
        const int itl   = ch * 2 + (gq >> 2);                 // k2>>4
        const int q     = gq & 3;                             // (k2>>2)&3
        const int chunk = ((lp >> 5) * 4 + q) * 32 + (lp & 31);
        *(uint4*)&ob[(size_t)itl * 2048 + chunk * 4] = wv;
    }
}

// ---------------- Kernel 2: bf16 MFMA GEMM, 3-buffer counted-vmcnt --------
// Fragment-major LDS; depth-2 prefetch ring so the steady-state wait is
// vmcnt(4) (retire only the tile being computed; next tile's loads stay in
// flight across the barrier). LDS 48 KB, VGPR ~= 2-buffer version.
__global__ __launch_bounds__(256)
void gemm_kernel(const uint32_t* __restrict__ Wnb, const uint32_t* __restrict__ xp,
                 uint32_t* __restrict__ fbp) {
    __shared__ uint32_t sA[3][2048];  // 24 KB
    __shared__ uint32_t sB[3][2048];  // 24 KB

    const int tid  = threadIdx.x;
    const int lane = tid & 63;
    const int w    = tid >> 6;
    const int wm   = w & 1, wn = w >> 1;

    const int bx  = blockIdx.x;
    const int xcd = bx & 7;
    const int t   = bx >> 3;
    const int o0t = t & 7;
    const int o0  = o0t * 128;
    const int ltg = xcd + ((t >> 3) << 3);
    const int l0  = ltg * 128;
    const int by  = blockIdx.y;  // local batch 0..3

    const uint32_t* gA = Wnb + (size_t)o0t * 32768 + (w * 2) * 256 + lane * 4;
    const uint32_t* gB = xp + (size_t)(by * 64 + ltg) * 32768 + (w * 2) * 256 + lane * 4;

    f32x16 acc[2][2];
#pragma unroll
    for (int i = 0; i < 2; ++i)
#pragma unroll
        for (int j = 0; j < 2; ++j)
#pragma unroll
            for (int r = 0; r < 16; ++r) acc[i][j][r] = 0.f;

#define STAGE(IT, BS)                                                     \
    do {                                                                  \
        gl_lds16(gA + (size_t)(IT) * 2048, &sA[BS][w * 512]);             \
        gl_lds16(gA + (size_t)(IT) * 2048 + 256, &sA[BS][w * 512 + 256]); \
        gl_lds16(gB + (size_t)(IT) * 2048, &sB[BS][w * 512]);             \
        gl_lds16(gB + (size_t)(IT) * 2048 + 256, &sB[BS][w * 512 + 256]); \
    } while (0)

#define COMPUTE(CB)                                                                    \
    do {                                                                               \
        _Pragma("unroll") for (int kh = 0; kh < 2; ++kh) {                             \
            bf16x8 af[2], bfr[2];                                                      \
            _Pragma("unroll") for (int ms = 0; ms < 2; ++ms)                           \
                af[ms] = *(const bf16x8*)&sA[CB][((wm * 2 + ms) * 4 + kh * 2) * 128 +  \
                                                 lane * 4];                            \
            _Pragma("unroll") for (int ns = 0; ns < 2; ++ns)                           \
                bfr[ns] = *(const bf16x8*)&sB[CB][((wn * 2 + ns) * 4 + kh * 2) * 128 + \
                                                  lane * 4];                           \
            _Pragma("unroll") for (int ms = 0; ms < 2; ++ms)                           \
                _Pragma("unroll") for (int ns = 0; ns < 2; ++ns)                       \
                    acc[ms][ns] = __builtin_amdgcn_mfma_f32_32x32x16_bf16(             \
                        af[ms], bfr[ns], acc[ms][ns], 0, 0, 0);                        \
        }                                                                              \
    } while (0)

// Steady state: outstanding = STAGE(it) + STAGE(it+1) = 8 loads;
// vmcnt(4) retires exactly STAGE(it). Buffer (IT+2)%3 was last read at
// step IT-1, completed by all waves before this barrier -> safe to stage.
#define STEP(IT, WN)                                             \
    do {                                                         \
        asm volatile("s_waitcnt vmcnt(" #WN ")" ::: "memory");   \
        __builtin_amdgcn_s_barrier();                            \
        __builtin_amdgcn_sched_barrier(0);                       \
        if ((IT) + 2 < 16) STAGE((IT) + 2, ((IT) + 2) % 3);      \
        COMPUTE((IT) % 3);                                       \
    } while (0)

    STAGE(0, 0);
    STAGE(1, 1);
    STEP(0, 4);  STEP(1, 4);  STEP(2, 4);  STEP(3, 4);
    STEP(4, 4);  STEP(5, 4);  STEP(6, 4);  STEP(7, 4);
    STEP(8, 4);  STEP(9, 4);  STEP(10, 4); STEP(11, 4);
    STEP(12, 4); STEP(13, 4); STEP(14, 4);
    STEP(15, 0);
#undef STEP
#undef COMPUTE
#undef STAGE

    // epilogue: pack adjacent-o pairs (adjacent acc regs) -> one uint32 word
    uint32_t* fbp_b = fbp + (size_t)by * 512 * LSEQ + l0;
#pragma unroll
    for (int ms = 0; ms < 2; ++ms)
#pragma unroll
        for (int ns = 0; ns < 2; ++ns) {
            const f32x16 a = acc[ms][ns];
            const int rb = o0 + wm * 64 + ms * 32 + 4 * (lane >> 5);  // even
            const int cc = wn * 64 + ns * 32 + (lane & 31);
#pragma unroll
            for (int rp = 0; rp < 8; ++rp) {
                const int r = rp * 2;
                const int row = rb + (r & 3) + 8 * (r >> 2);  // even
                fbp_b[(size_t)(row >> 1) * LSEQ + cc] = pack_bf16_rne(a[r], a[r + 1]);
            }
        }
}

// ---------------- Kernel 3: minGRU scan, direct-load version --------------
__global__ __launch_bounds__(1024)
void scan_kernel(const uint32_t* __restrict__ fbp, float* __restrict__ out, int b0) {
    __shared__ float sA0[16], sB0[16], sA1[16], sB1[16];

    const int bx  = blockIdx.x;  // 0..255
    const int by  = blockIdx.y;  // local batch 0..3
    const int b   = b0 + by;     // global batch
    const int dir = bx >> 7;
    const int p   = bx & 127;
    const int o2h = dir * 256 + p;
    const int o2g = dir * 256 + 128 + p;

    const int t    = threadIdx.x;  // 0..1023
    const int lane = t & 63;
    const int w    = t >> 6;       // 0..15

    const uint32_t* hp = fbp + ((size_t)by * 512 + o2h) * LSEQ + t * 8;
    const uint32_t* gp = fbp + ((size_t)by * 512 + o2g) * LSEQ + t * 8;
    const uint4 h4a = *(const uint4*)(hp);
    const uint4 h4b = *(const uint4*)(hp + 4);
    const uint4 g4a = *(const uint4*)(gp);
    const uint4 g4b = *(const uint4*)(gp + 4);

    float av0[8], vv0[8], av1[8], vv1[8];
    {
        const uint32_t hws[8] = {h4a.x, h4a.y, h4a.z, h4a.w, h4b.x, h4b.y, h4b.z, h4b.w};
        const uint32_t gws[8] = {g4a.x, g4a.y, g4a.z, g4a.w, g4b.x, g4b.y, g4b.z, g4b.w};
#pragma unroll
        for (int s = 0; s < 8; ++s) {
            {
                float g_ = fminf(fmaxf(bf16_lo(gws[s]), -30.f), 30.f);
                float eg = __expf(g_);
                float a  = rsqrtf(fmaf(eg, eg, 1.f));
                float h_ = bf16_lo(hws[s]);
                av0[s] = a;
                vv0[s] = a * eg * copysignf(fmaxf(fabsf(h_), 1e-6f), h_);
            }
            {
                float g_ = fminf(fmaxf(bf16_hi(gws[s]), -30.f), 30.f);
                float eg = __expf(g_);
                float a  = rsqrtf(fmaf(eg, eg, 1.f));
                float h_ = bf16_hi(hws[s]);
                av1[s] = a;
                vv1[s] = a * eg * copysignf(fmaxf(fabsf(h_), 1e-6f), h_);
            }
        }
    }

    // ---- local composites (scan order) ----
    float A0 = 1.f, B0 = 0.f, A1 = 1.f, B1 = 0.f;
    if (dir == 0) {
#pragma unroll
        for (int i = 0; i < 8; ++i) {
            B0 = fmaf(av0[i], B0, vv0[i]); A0 *= av0[i];
            B1 = fmaf(av1[i], B1, vv1[i]); A1 *= av1[i];
        }
    } else {
#pragma unroll
        for (int i = 7; i >= 0; --i) {
            B0 = fmaf(av0[i], B0, vv0[i]); A0 *= av0[i];
            B1 = fmaf(av1[i], B1, vv1[i]); A1 *= av1[i];
        }
    }

    // ---- wave scan of affine composites ----
    if (dir == 0) {
#pragma unroll
        for (int off = 1; off < 64; off <<= 1) {
            float Ap0 = __shfl_up(A0, (unsigned)off, 64), Bp0 = __shfl_up(B0, (unsigned)off, 64);
            float Ap1 = __shfl_up(A1, (unsigned)off, 64), Bp1 = __shfl_up(B1, (unsigned)off, 64);
            if (lane >= off) {
                B0 = fmaf(A0, Bp0, B0); A0 *= Ap0;
                B1 = fmaf(A1, Bp1, B1); A1 *= Ap1;
            }
        }
        if (lane == 63) { sA0[w] = A0; sB0[w] = B0; sA1[w] = A1; sB1[w] = B1; }
    } else {
#pragma unroll
        for (int off = 1; off < 64; off <<= 1) {
            float Ap0 = __shfl_down(A0, (unsigned)off, 64), Bp0 = __shfl_down(B0, (unsigned)off, 64);
            float Ap1 = __shfl_down(A1, (unsigned)off, 64), Bp1 = __shfl_down(B1, (unsigned)off, 64);
            if (lane + off < 64) {
                B0 = fmaf(A0, Bp0, B0); A0 *= Ap0;
                B1 = fmaf(A1, Bp1, B1); A1 *= Ap1;
            }
        }
        if (lane == 0) { sA0[w] = A0; sB0[w] = B0; sA1[w] = A1; sB1[w] = B1; }
    }
    __syncthreads();

    // ---- cross-wave combine (16 waves) ----
    float WB0 = 0.f, WB1 = 0.f;
    if (dir == 0) {
        for (int wv = 0; wv < w; ++wv) {
            WB0 = fmaf(sA0[wv], WB0, sB0[wv]);
            WB1 = fmaf(sA1[wv], WB1, sB1[wv]);
        }
    } else {
        for (int wv = 15; wv > w; --wv) {
            WB0 = fmaf(sA0[wv], WB0, sB0[wv]);
            WB1 = fmaf(sA1[wv], WB1, sB1[wv]);
        }
    }
    float eA0, eB0, eA1, eB1;
    if (dir == 0) {
        eA0 = __shfl_up(A0, 1u, 64); eB0 = __shfl_up(B0, 1u, 64);
        eA1 = __shfl_up(A1, 1u, 64); eB1 = __shfl_up(B1, 1u, 64);
        if (lane == 0) { eA0 = 1.f; eB0 = 0.f; eA1 = 1.f; eB1 = 0.f; }
    } else {
        eA0 = __shfl_down(A0, 1u, 64); eB0 = __shfl_down(B0, 1u, 64);
        eA1 = __shfl_down(A1, 1u, 64); eB1 = __shfl_down(B1, 1u, 64);
        if (lane == 63) { eA0 = 1.f; eB0 = 0.f; eA1 = 1.f; eB1 = 0.f; }
    }
    float H0 = fmaf(eA0, WB0, eB0);
    float H1 = fmaf(eA1, WB1, eB1);

    // ---- final replay (results into vv, memory order) ----
    if (dir == 0) {
#pragma unroll
        for (int i = 0; i < 8; ++i) {
            H0 = fmaf(av0[i], H0, vv0[i]); vv0[i] = H0;
            H1 = fmaf(av1[i], H1, vv1[i]); vv1[i] = H1;
        }
    } else {
#pragma unroll
        for (int i = 7; i >= 0; --i) {
            H0 = fmaf(av0[i], H0, vv0[i]); vv0[i] = H0;
            H1 = fmaf(av1[i], H1, vv1[i]); vv1[i] = H1;
        }
    }

    // ---- direct stores ----
    float* orow0 = out + ((size_t)b * 512 + dir * 256 + 2 * p) * LSEQ + t * 8;
    float* orow1 = orow0 + LSEQ;  // channel 2p+1
    *(float4*)(orow0)     = make_float4(vv0[0], vv0[1], vv0[2], vv0[3]);
    *(float4*)(orow0 + 4) = make_float4(vv0[4], vv0[5], vv0[6], vv0[7]);
    *(float4*)(orow1)     = make_float4(vv1[0], vv1[1], vv1[2], vv1[3]);
    *(float4*)(orow1 + 4) = make_float4(vv1[4], vv1[5], vv1[6], vv1[7]);
}

// ---------------- launch ----------------
// Batch-sliced (2 halves x 4 batches): xp/fbp hold only the live half so the
// gemm->scan intermediate stays L3-resident.
extern "C" void kernel_launch(void* const* d_in, const int* in_sizes, int n_in,
                              void* d_out, int out_size, void* d_ws, size_t ws_size,
                              hipStream_t stream) {
    const float* x = (const float*)d_in[0];  // (8, 512, 8192)
    const float* W = (const float*)d_in[1];  // (1024, 512, 1)
    float* out = (float*)d_out;              // (8, 512, 8192)

    uint32_t* Wnb = (uint32_t*)d_ws;                                   // 1 MB
    uint32_t* fbp = (uint32_t*)((char*)d_ws + (size_t)NO * DIN * 2);   // 67 MB
    uint32_t* xp  = (uint32_t*)((char*)d_ws + (size_t)NO * DIN * 2
                                + (size_t)NBH * 512 * LSEQ * 4);       // 32 MB

    norm_kernel<<<dim3(NO), dim3(64), 0, stream>>>(W, Wnb);
    for (int h = 0; h < 2; ++h) {
        xpack_kernel<<<dim3(512, NBH), dim3(256), 0, stream>>>(x, xp, h * NBH);
        gemm_kernel<<<dim3(512, NBH), dim3(256), 0, stream>>>(Wnb, xp, fbp);
        scan_kernel<<<dim3(256, NBH), dim3(1024), 0, stream>>>(fbp, out, h * NBH);
    }
}